// Round 2
// baseline (610.179 us; speedup 1.0000x reference)
//
#include <hip/hip_runtime.h>

#define N_NODES 500000
#define N_EDGES 5000000
#define D 16
#define SCAN_B 512
#define NBLK ((N_NODES + SCAN_B - 1) / SCAN_B)   // 977

// ===================== CSR-build + gather path =====================

// Phase A: per-destination degree count (int atomics, 2MB counter array).
__global__ void count_k(const int* __restrict__ edst, int* __restrict__ cnt) {
    int e = blockIdx.x * blockDim.x + threadIdx.x;
    if (e < N_EDGES) atomicAdd(&cnt[edst[e]], 1);
}

// Phase B1: per-block (512-wide) sums of cnt.
__global__ void block_sums_k(const int* __restrict__ cnt, int* __restrict__ bsum) {
    __shared__ int ws[8];
    int t = threadIdx.x;
    int i = blockIdx.x * SCAN_B + t;
    int v = (i < N_NODES) ? cnt[i] : 0;
#pragma unroll
    for (int off = 32; off; off >>= 1) v += __shfl_down(v, off, 64);
    if ((t & 63) == 0) ws[t >> 6] = v;
    __syncthreads();
    if (t == 0) {
        int s = 0;
#pragma unroll
        for (int j = 0; j < 8; ++j) s += ws[j];
        bsum[blockIdx.x] = s;
    }
}

// Phase B2: exclusive scan of the 977 block sums, single block.
__global__ void scan_bsums_k(int* __restrict__ bsum) {
    __shared__ int s[1024];
    int t = threadIdx.x;
    int v = (t < NBLK) ? bsum[t] : 0;
    s[t] = v;
    __syncthreads();
    for (int off = 1; off < 1024; off <<= 1) {
        int u = (t >= off) ? s[t - off] : 0;
        __syncthreads();
        s[t] += u;
        __syncthreads();
    }
    if (t < NBLK) bsum[t] = s[t] - v;   // exclusive
}

// Phase B3: per-block exclusive scan + block offset -> global row offsets.
__global__ void scan_offsets_k(const int* __restrict__ cnt, const int* __restrict__ bsum,
                               int* __restrict__ offs) {
    __shared__ int s[SCAN_B];
    int b = blockIdx.x, t = threadIdx.x;
    int i = b * SCAN_B + t;
    int v = (i < N_NODES) ? cnt[i] : 0;
    s[t] = v;
    __syncthreads();
    for (int off = 1; off < SCAN_B; off <<= 1) {
        int u = (t >= off) ? s[t - off] : 0;
        __syncthreads();
        s[t] += u;
        __syncthreads();
    }
    if (i < N_NODES) offs[i] = bsum[b] + (s[t] - v);
}

// Phase C: scatter edge sources into CSR slots (int atomics on cursors).
__global__ void fill_slots_k(const int* __restrict__ esrc, const int* __restrict__ edst,
                             const int* __restrict__ offs, int* __restrict__ cursor,
                             int* __restrict__ slots) {
    int e = blockIdx.x * blockDim.x + threadIdx.x;
    if (e >= N_EDGES) return;
    int t = edst[e];
    int p = atomicAdd(&cursor[t], 1);
    slots[offs[t] + p] = esrc[e];
}

// Phase D: gather-mean + fused finalize. 16 lanes per node; lane d owns dim d.
// Slots are chunk-preloaded (one per lane) and broadcast with shfl(width=16),
// so the only per-edge memory op is one coalesced 64B read of x[src].
__global__ __launch_bounds__(256) void gather_finalize_k(
    const float* __restrict__ x, const int* __restrict__ slots,
    const int* __restrict__ offs, const int* __restrict__ cnt,
    const float* __restrict__ W_l, const float* __restrict__ b_l,
    const float* __restrict__ W_r, float* __restrict__ out) {
    int tid = blockIdx.x * blockDim.x + threadIdx.x;
    int g = tid >> 4;
    int d = tid & 15;
    if (g >= N_NODES) return;

    // Weight row d of each matrix into registers (L1-broadcast across blocks).
    float wl[D], wr[D];
    const float4* wl4 = (const float4*)(W_l + d * D);
    const float4* wr4 = (const float4*)(W_r + d * D);
#pragma unroll
    for (int q = 0; q < 4; ++q) {
        float4 a = wl4[q], b = wr4[q];
        wl[4*q+0]=a.x; wl[4*q+1]=a.y; wl[4*q+2]=a.z; wl[4*q+3]=a.w;
        wr[4*q+0]=b.x; wr[4*q+1]=b.y; wr[4*q+2]=b.z; wr[4*q+3]=b.w;
    }

    int beg = offs[g], n = cnt[g];
    float acc = 0.f;
    for (int e0 = 0; e0 < n; e0 += 16) {
        int c = n - e0; if (c > 16) c = 16;
        int myslot = (d < c) ? slots[beg + e0 + d] : 0;
        for (int e = 0; e < c; ++e) {
            int s = __shfl(myslot, e, 16);
            acc += x[s * D + d];           // 16 lanes -> one 64B segment
        }
    }
    float m  = acc / fmaxf((float)n, 1.0f);
    float xv = x[g * D + d];

    float o = b_l[d];
#pragma unroll
    for (int k = 0; k < D; ++k) {
        float mk = __shfl(m, k, 16);
        float xk = __shfl(xv, k, 16);
        o += mk * wl[k] + xk * wr[k];
    }
    out[g * D + d] = o;
}

// ===================== fallback (R1 atomic path) =====================

__global__ void sage_scatter(const float* __restrict__ x, const int* __restrict__ esrc,
                             const int* __restrict__ edst, float* __restrict__ agg,
                             float* __restrict__ cnt) {
    long long gid = (long long)blockIdx.x * blockDim.x + threadIdx.x;
    long long e = gid >> 4;
    int d = (int)(gid & 15);
    if (e >= N_EDGES) return;
    atomicAdd(&agg[(long long)edst[e] * D + d], x[(long long)esrc[e] * D + d]);
    if (d == 0) atomicAdd(&cnt[edst[e]], 1.0f);
}

__global__ void sage_finalize(const float* __restrict__ x, float* __restrict__ agg_out,
                              const float* __restrict__ cnt, const float* __restrict__ W_l,
                              const float* __restrict__ b_l, const float* __restrict__ W_r) {
    __shared__ float sWl[D * D], sWr[D * D], sb[D];
    int tid = threadIdx.x;
    if (tid < D * D) { sWl[tid] = W_l[tid]; sWr[tid] = W_r[tid]; }
    if (tid < D) sb[tid] = b_l[tid];
    __syncthreads();
    int i = blockIdx.x * blockDim.x + tid;
    if (i >= N_NODES) return;
    float inv = 1.0f / fmaxf(cnt[i], 1.0f);
    float m[D], xv[D];
    const float4* ap = (const float4*)(agg_out + (long long)i * D);
    const float4* xp = (const float4*)(x + (long long)i * D);
#pragma unroll
    for (int q = 0; q < 4; ++q) {
        float4 a = ap[q], b = xp[q];
        m[4*q+0]=a.x*inv; m[4*q+1]=a.y*inv; m[4*q+2]=a.z*inv; m[4*q+3]=a.w*inv;
        xv[4*q+0]=b.x; xv[4*q+1]=b.y; xv[4*q+2]=b.z; xv[4*q+3]=b.w;
    }
    float o[D];
#pragma unroll
    for (int oo = 0; oo < D; ++oo) {
        float a2 = sb[oo];
#pragma unroll
        for (int k = 0; k < D; ++k) a2 += m[k]*sWl[oo*D+k] + xv[k]*sWr[oo*D+k];
        o[oo] = a2;
    }
    float4* op = (float4*)(agg_out + (long long)i * D);
#pragma unroll
    for (int q = 0; q < 4; ++q)
        op[q] = make_float4(o[4*q+0], o[4*q+1], o[4*q+2], o[4*q+3]);
}

// ===================== launch =====================

extern "C" void kernel_launch(void* const* d_in, const int* in_sizes, int n_in,
                              void* d_out, int out_size, void* d_ws, size_t ws_size,
                              hipStream_t stream) {
    const float* x   = (const float*)d_in[0];
    const int*   ei  = (const int*)d_in[1];
    const float* W_l = (const float*)d_in[2];
    const float* b_l = (const float*)d_in[3];
    const float* W_r = (const float*)d_in[4];
    const int* esrc = ei;
    const int* edst = ei + N_EDGES;
    float* out = (float*)d_out;

    // workspace layout (ints): cnt | offs | cursor | bsum(1024) | slots
    size_t need = ((size_t)3 * N_NODES + 1024 + N_EDGES) * sizeof(int);

    if (ws_size >= need) {
        int* cnt    = (int*)d_ws;
        int* offs   = cnt + N_NODES;
        int* cursor = offs + N_NODES;
        int* bsum   = cursor + N_NODES;
        int* slots  = bsum + 1024;

        hipMemsetAsync(cnt, 0, (size_t)N_NODES * sizeof(int), stream);
        hipMemsetAsync(cursor, 0, (size_t)N_NODES * sizeof(int), stream);

        count_k<<<(N_EDGES + 255) / 256, 256, 0, stream>>>(edst, cnt);
        block_sums_k<<<NBLK, SCAN_B, 0, stream>>>(cnt, bsum);
        scan_bsums_k<<<1, 1024, 0, stream>>>(bsum);
        scan_offsets_k<<<NBLK, SCAN_B, 0, stream>>>(cnt, bsum, offs);
        fill_slots_k<<<(N_EDGES + 255) / 256, 256, 0, stream>>>(esrc, edst, offs, cursor, slots);

        unsigned grid = (unsigned)(((long long)N_NODES * D + 255) / 256);
        gather_finalize_k<<<grid, 256, 0, stream>>>(x, slots, offs, cnt, W_l, b_l, W_r, out);
    } else {
        // fallback: R1 atomic path (needs only 2MB of ws)
        float* cntf = (float*)d_ws;
        hipMemsetAsync(out, 0, (size_t)N_NODES * D * sizeof(float), stream);
        hipMemsetAsync(cntf, 0, (size_t)N_NODES * sizeof(float), stream);
        long long total = (long long)N_EDGES * D;
        sage_scatter<<<(unsigned)((total + 255) / 256), 256, 0, stream>>>(x, esrc, edst, out, cntf);
        sage_finalize<<<(N_NODES + 255) / 256, 256, 0, stream>>>(x, out, cntf, W_l, b_l, W_r);
    }
}